// Round 1
// baseline (823.593 us; speedup 1.0000x reference)
//
#include <hip/hip_runtime.h>
#include <cstdint>
#include <cstddef>

// ---------------------------------------------------------------------------
// AdaptiveLSTMCell (B=4096, I=1024, H=1024, AH=128, AI=16), fp32 in/out.
// Strategy:
//   * big GEMMs via bf16 MFMA with 3-term hi/lo split (K -> 3K concat trick):
//       C = Ahi*Bhi + Ahi*Blo + Alo*Bhi  (error ~2^-16, safe vs fp32 ref)
//   * m97-style 128x128 tile GEMM, BK=32, global_load_lds(16B) staging
//   * adaptive path (LN512 x2, gate, LN128, zw/zb) fused per-row (1 wave/row)
//   * alpha/beta NEVER materialized: fused scale+stats kernel updates xh/hh
//     in place (8 rows/block to amortize the 1MB norm/bias weight stream)
//   * final gates kernel: LN4096 (stats precomputed), gate math, LN1024, out
// ---------------------------------------------------------------------------

#define B_   4096
#define I_   1024
#define H_   1024
#define AH_  128
#define AI_  16
#define G4_  4096   // 4*H
#define EPS_ 1e-5f

// out layout: hy (B*H) | new_total_h (B*1152) | new_total_c (B*1152)
#define OUT_TH ((size_t)B_ * H_)
#define OUT_TC (OUT_TH + (size_t)B_ * (H_ + AH_))

typedef short s16x8 __attribute__((ext_vector_type(8)));
typedef float f32x4 __attribute__((ext_vector_type(4)));

// ---------------- helpers ----------------
__device__ __forceinline__ unsigned short f2bf_rn(float f) {
    unsigned int u = __builtin_bit_cast(unsigned int, f);
    unsigned int r = u + 0x7FFFu + ((u >> 16) & 1u);   // round-to-nearest-even
    return (unsigned short)(r >> 16);
}
__device__ __forceinline__ float bf2f(unsigned short h) {
    unsigned int u = ((unsigned int)h) << 16;
    return __builtin_bit_cast(float, u);
}
__device__ __forceinline__ float sigf(float x) { return 1.0f / (1.0f + expf(-x)); }

__device__ __forceinline__ void gld16(const void* g, void* l) {
    __builtin_amdgcn_global_load_lds(
        (const __attribute__((address_space(1))) unsigned int*)g,
        (__attribute__((address_space(3))) unsigned int*)l,
        16, 0, 0);
}

// ---------------- split: fp32 -> bf16 hi/lo panels ----------------
// writes hi at offHiA and offHiB, lo at offLo (col offsets in dst row)
__global__ void split3_kernel(const float* __restrict__ src, int srcStride, int srcOff,
                              long total, int K,
                              unsigned short* __restrict__ dst, int dstStride,
                              int offHiA, int offHiB, int offLo) {
    long idx = (long)blockIdx.x * blockDim.x + threadIdx.x;
    if (idx >= total) return;
    int r = (int)(idx / K);
    int k = (int)(idx - (long)r * K);
    float v = src[(size_t)r * srcStride + srcOff + k];
    unsigned short hu = f2bf_rn(v);
    unsigned short lu = f2bf_rn(v - bf2f(hu));
    size_t base = (size_t)r * dstStride;
    dst[base + offHiA + k] = hu;
    dst[base + offHiB + k] = hu;
    dst[base + offLo  + k] = lu;
}

// ---------------- GEMM: C(MxN) = A(MxK) * W(NxK)^T, bf16 in, fp32 out -------
// A is two K-chunks: A0 for k<kSplit, A1 for k>=kSplit (both row stride lda).
__launch_bounds__(256, 2)
__global__ void gemm_bt_bf16(const unsigned short* __restrict__ A0,
                             const unsigned short* __restrict__ A1,
                             int kSplit, int lda,
                             const unsigned short* __restrict__ W, int ldw,
                             float* __restrict__ C, int ldc, int K) {
    __shared__ __align__(16) unsigned short As[128 * 32];
    __shared__ __align__(16) unsigned short Bs[128 * 32];
    const int tid  = threadIdx.x;
    const int lane = tid & 63;
    const int w    = tid >> 6;          // wave 0..3
    const int wr   = w >> 1, wc = w & 1; // wave -> 64x64 quadrant
    const int bx   = blockIdx.x, by = blockIdx.y;
    const int l15  = lane & 15;
    const int lk   = (lane >> 4) * 8;

    f32x4 acc[4][4] = {};

    for (int kt = 0; kt < K; kt += 32) {
        const unsigned short* Ab = (kt < kSplit) ? (A0 + kt) : (A1 + (kt - kSplit));
        const unsigned short* Wb = W + kt;
#pragma unroll
        for (int it = 0; it < 2; ++it) {
            int q = it * 256 + tid;
            int row = q >> 2, c8 = (q & 3) * 8;
            gld16(Ab + (size_t)(by * 128 + row) * lda + c8,
                  (char*)As + (size_t)(it * 256 + w * 64) * 16);
        }
#pragma unroll
        for (int it = 0; it < 2; ++it) {
            int q = it * 256 + tid;
            int row = q >> 2, c8 = (q & 3) * 8;
            gld16(Wb + (size_t)(bx * 128 + row) * ldw + c8,
                  (char*)Bs + (size_t)(it * 256 + w * 64) * 16);
        }
        __syncthreads();   // compiler drains vmcnt before barrier

        s16x8 afr[4], bfr[4];
#pragma unroll
        for (int m = 0; m < 4; ++m)
            afr[m] = *(const s16x8*)&As[(wr * 64 + m * 16 + l15) * 32 + lk];
#pragma unroll
        for (int n = 0; n < 4; ++n)
            bfr[n] = *(const s16x8*)&Bs[(wc * 64 + n * 16 + l15) * 32 + lk];
#pragma unroll
        for (int m = 0; m < 4; ++m)
#pragma unroll
            for (int n = 0; n < 4; ++n)
                acc[m][n] = __builtin_amdgcn_mfma_f32_16x16x32_bf16(
                    afr[m], bfr[n], acc[m][n], 0, 0, 0);
        __syncthreads();
    }

    const int r0 = by * 128 + wr * 64;
    const int c0 = bx * 128 + wc * 64;
    const int rl = (lane >> 4) * 4;
#pragma unroll
    for (int m = 0; m < 4; ++m)
#pragma unroll
        for (int n = 0; n < 4; ++n)
#pragma unroll
            for (int j = 0; j < 4; ++j)
                C[(size_t)(r0 + m * 16 + rl + j) * ldc + c0 + n * 16 + l15] = acc[m][n][j];
}

// ---------------- adaptive path: LN(ig)+LN(hg) -> gates -> acy/ada -> zw/zb -
// one wave per batch row
__launch_bounds__(64)
__global__ void adaptive_gates_kernel(const float* __restrict__ IG, const float* __restrict__ HG,
                                      const float* __restrict__ total_c,
                                      const float* __restrict__ alniw, const float* __restrict__ alnib,
                                      const float* __restrict__ alnhw, const float* __restrict__ alnhb,
                                      const float* __restrict__ alncw, const float* __restrict__ alncb,
                                      const float* __restrict__ zw_w, const float* __restrict__ zw_b,
                                      const float* __restrict__ zb_w,
                                      float* __restrict__ ZW, float* __restrict__ ZB,
                                      float* __restrict__ out) {
    const int b    = blockIdx.x;
    const int lane = threadIdx.x;
    __shared__ float ada_lds[AH_];

    // each lane holds 8 consecutive of the 512 gate pre-acts
    float ig[8], hg[8];
    const float* igp = IG + (size_t)b * 512 + lane * 8;
    const float* hgp = HG + (size_t)b * 512 + lane * 8;
    float sI = 0, qI = 0, sH = 0, qH = 0;
#pragma unroll
    for (int j = 0; j < 8; ++j) {
        ig[j] = igp[j]; sI += ig[j]; qI += ig[j] * ig[j];
        hg[j] = hgp[j]; sH += hg[j]; qH += hg[j] * hg[j];
    }
#pragma unroll
    for (int m = 1; m < 64; m <<= 1) {
        sI += __shfl_xor(sI, m); qI += __shfl_xor(qI, m);
        sH += __shfl_xor(sH, m); qH += __shfl_xor(qH, m);
    }
    const float muI = sI * (1.0f / 512.0f);
    const float rI  = rsqrtf(qI * (1.0f / 512.0f) - muI * muI + EPS_);
    const float muH = sH * (1.0f / 512.0f);
    const float rH  = rsqrtf(qH * (1.0f / 512.0f) - muH * muH + EPS_);

    float g[8];
#pragma unroll
    for (int j = 0; j < 8; ++j) {
        int c = lane * 8 + j;
        g[j] = (ig[j] - muI) * rI * alniw[c] + alnib[c]
             + (hg[j] - muH) * rH * alnhw[c] + alnhb[c];
    }

    // adaptive gate split order: gi, gf, gj, go  (chunks 0,1,2,3 of 512)
    const int l15 = lane & 15;
    float cp[8], gov[8];
    float s = 0, q = 0;
#pragma unroll
    for (int j = 0; j < 8; ++j) {
        float giv = __shfl(g[j], l15);
        float gfv = __shfl(g[j], 16 + l15);
        float gjv = __shfl(g[j], 32 + l15);
        gov[j]    = __shfl(g[j], 48 + l15);
        int a = l15 * 8 + j;
        float ac = total_c[(size_t)b * (H_ + AH_) + H_ + a];
        cp[j] = sigf(gfv) * ac + sigf(giv) * tanhf(gjv);
        s += cp[j]; q += cp[j] * cp[j];
    }
    // reduce over each aligned 16-lane group (each group holds a full replica)
#pragma unroll
    for (int m = 1; m < 16; m <<= 1) { s += __shfl_xor(s, m); q += __shfl_xor(q, m); }
    const float mu = s * (1.0f / 128.0f);
    const float rs = rsqrtf(q * (1.0f / 128.0f) - mu * mu + EPS_);

    float adav[8], acyv[8];
#pragma unroll
    for (int j = 0; j < 8; ++j) {
        int a = l15 * 8 + j;
        acyv[j] = (cp[j] - mu) * rs * alncw[a] + alncb[a];
        adav[j] = sigf(gov[j]) * tanhf(acyv[j]);
    }
    if (lane < 16) {
#pragma unroll
        for (int j = 0; j < 8; ++j) {
            int a = lane * 8 + j;
            ada_lds[a] = adav[j];
            out[OUT_TH + (size_t)b * (H_ + AH_) + H_ + a] = adav[j];  // ada
            out[OUT_TC + (size_t)b * (H_ + AH_) + H_ + a] = acyv[j]; // acy
        }
    }
    __syncthreads();

    // zw[b,idx] = sum_a ada[a]*zw_w[idx,a] + zw_b[idx];  zb likewise (no bias)
#pragma unroll
    for (int t = 0; t < 2; ++t) {
        int idx = lane * 2 + t;                 // 0..127 = s*16+i
        const float* wz = zw_w + (size_t)idx * AH_;
        const float* wb = zb_w + (size_t)idx * AH_;
        float az = 0, ab = 0;
        for (int a = 0; a < AH_; ++a) {
            float ad = ada_lds[a];
            az += ad * wz[a];
            ab += ad * wb[a];
        }
        ZW[(size_t)b * 128 + idx] = az + zw_b[idx];
        ZB[(size_t)b * 128 + idx] = ab;
    }
}

// ---------------- scale xh/hh by alpha,+bias+beta (in place) + row stats ----
// 8 rows per block; weights streamed once per block (amortized over rows)
__launch_bounds__(512)
__global__ void scale_stats_kernel(float* __restrict__ XH, float* __restrict__ HH,
                                   const float* __restrict__ ZW, const float* __restrict__ ZB,
                                   const float* __restrict__ aw, const float* __restrict__ bw,
                                   const float* __restrict__ b_ih, const float* __restrict__ b_hh,
                                   float* __restrict__ STATS) {
    const int tid  = threadIdx.x;
    const int lane = tid & 63;
    const int w    = tid >> 6;     // 8 waves
    const int b0   = blockIdx.x * 8;

    __shared__ float zwl[8 * 128], zbl[8 * 128];
    __shared__ float part[8][8][4];
    __shared__ float tot[8][4];

    for (int t = tid; t < 1024; t += 512) {
        int r = t >> 7, si = t & 127;
        zwl[t] = ZW[(size_t)(b0 + r) * 128 + si];
        zbl[t] = ZB[(size_t)(b0 + r) * 128 + si];
    }
    __syncthreads();

    float sI[8] = {}, qI[8] = {}, sH[8] = {}, qH[8] = {};

    for (int strip = w; strip < 128; strip += 8) {   // 64 in_g strips, 64 hid_g
        const bool isIn = strip < 64;
        const int  c    = (isIn ? strip : strip - 64) * 64 + lane;   // 0..4095
        const int  se   = (c >> 10) + (isIn ? 0 : 4);                // s index 0..7
        float*       X    = isIn ? XH : HH;
        const float* bias = isIn ? b_ih : b_hh;
        const int    h    = c & 1023;

        const f32x4* awp = (const f32x4*)(aw + ((size_t)se * 1024 + h) * 16);
        const f32x4* bwp = (const f32x4*)(bw + ((size_t)se * 1024 + h) * 16);
        f32x4 a0 = awp[0], a1 = awp[1], a2 = awp[2], a3 = awp[3];
        f32x4 w0 = bwp[0], w1 = bwp[1], w2 = bwp[2], w3 = bwp[3];
        const float bc = bias[c];

#pragma unroll
        for (int r = 0; r < 8; ++r) {
            const float* z  = &zwl[r * 128 + se * 16];
            const float* zb = &zbl[r * 128 + se * 16];
            float alpha = a0[0]*z[0]  + a0[1]*z[1]  + a0[2]*z[2]  + a0[3]*z[3]
                        + a1[0]*z[4]  + a1[1]*z[5]  + a1[2]*z[6]  + a1[3]*z[7]
                        + a2[0]*z[8]  + a2[1]*z[9]  + a2[2]*z[10] + a2[3]*z[11]
                        + a3[0]*z[12] + a3[1]*z[13] + a3[2]*z[14] + a3[3]*z[15];
            float beta  = w0[0]*zb[0]  + w0[1]*zb[1]  + w0[2]*zb[2]  + w0[3]*zb[3]
                        + w1[0]*zb[4]  + w1[1]*zb[5]  + w1[2]*zb[6]  + w1[3]*zb[7]
                        + w2[0]*zb[8]  + w2[1]*zb[9]  + w2[2]*zb[10] + w2[3]*zb[11]
                        + w3[0]*zb[12] + w3[1]*zb[13] + w3[2]*zb[14] + w3[3]*zb[15];
            size_t off = (size_t)(b0 + r) * G4_ + c;
            float v = X[off] * alpha + bc + beta;
            X[off] = v;
            if (isIn) { sI[r] += v; qI[r] += v * v; }
            else      { sH[r] += v; qH[r] += v * v; }
        }
    }

#pragma unroll
    for (int r = 0; r < 8; ++r) {
#pragma unroll
        for (int m = 1; m < 64; m <<= 1) {
            sI[r] += __shfl_xor(sI[r], m); qI[r] += __shfl_xor(qI[r], m);
            sH[r] += __shfl_xor(sH[r], m); qH[r] += __shfl_xor(qH[r], m);
        }
        if (lane == 0) {
            part[w][r][0] = sI[r]; part[w][r][1] = qI[r];
            part[w][r][2] = sH[r]; part[w][r][3] = qH[r];
        }
    }
    __syncthreads();
    if (tid < 32) {
        int r = tid >> 2, cmp = tid & 3;
        float t = 0;
        for (int ww = 0; ww < 8; ++ww) t += part[ww][r][cmp];
        tot[r][cmp] = t;
    }
    __syncthreads();
    if (tid < 8) {
        int r = tid;
        float muI = tot[r][0] * (1.0f / 4096.0f);
        float vI  = tot[r][1] * (1.0f / 4096.0f) - muI * muI;
        float muH = tot[r][2] * (1.0f / 4096.0f);
        float vH  = tot[r][3] * (1.0f / 4096.0f) - muH * muH;
        f32x4 st = { muI, rsqrtf(vI + EPS_), muH, rsqrtf(vH + EPS_) };
        *(f32x4*)(STATS + (size_t)(b0 + r) * 4) = st;
    }
}

// ---------------- final: LN(in_g)+LN(hid_g) -> LSTM gates -> LN(c) -> out ---
__launch_bounds__(256)
__global__ void final_gates_kernel(const float* __restrict__ XH, const float* __restrict__ HH,
                                   const float* __restrict__ STATS,
                                   const float* __restrict__ lniw, const float* __restrict__ lnib,
                                   const float* __restrict__ lnhw, const float* __restrict__ lnhb,
                                   const float* __restrict__ lncw, const float* __restrict__ lncb,
                                   const float* __restrict__ total_c,
                                   float* __restrict__ out) {
    const int b = blockIdx.x, tid = threadIdx.x;
    const int lane = tid & 63, w = tid >> 6;
    __shared__ float red[4][2];

    const f32x4 st = *(const f32x4*)(STATS + (size_t)b * 4); // muI,rI,muH,rH
    const int h0 = tid * 4;

    float gg[4][4];
#pragma unroll
    for (int s = 0; s < 4; ++s) {
        int c = s * 1024 + h0;
        f32x4 xi = *(const f32x4*)(XH + (size_t)b * G4_ + c);
        f32x4 hi = *(const f32x4*)(HH + (size_t)b * G4_ + c);
        f32x4 wi = *(const f32x4*)(lniw + c);
        f32x4 bi = *(const f32x4*)(lnib + c);
        f32x4 wh = *(const f32x4*)(lnhw + c);
        f32x4 bh = *(const f32x4*)(lnhb + c);
#pragma unroll
        for (int e = 0; e < 4; ++e)
            gg[s][e] = (xi[e] - st[0]) * st[1] * wi[e] + bi[e]
                     + (hi[e] - st[2]) * st[3] * wh[e] + bh[e];
    }

    // main LSTM split order: i, j, f, o (chunks 0,1,2,3)
    float cp[4], ov[4];
    float s_ = 0, q_ = 0;
#pragma unroll
    for (int e = 0; e < 4; ++e) {
        float iv = gg[0][e], jv = gg[1][e], fv = gg[2][e];
        ov[e] = gg[3][e];
        float cx = total_c[(size_t)b * (H_ + AH_) + h0 + e];
        cp[e] = sigf(fv) * cx + sigf(iv) * tanhf(jv);
        s_ += cp[e]; q_ += cp[e] * cp[e];
    }
#pragma unroll
    for (int m = 1; m < 64; m <<= 1) { s_ += __shfl_xor(s_, m); q_ += __shfl_xor(q_, m); }
    if (lane == 0) { red[w][0] = s_; red[w][1] = q_; }
    __syncthreads();
    float S = red[0][0] + red[1][0] + red[2][0] + red[3][0];
    float Q = red[0][1] + red[1][1] + red[2][1] + red[3][1];
    float mu = S * (1.0f / 1024.0f);
    float rs = rsqrtf(Q * (1.0f / 1024.0f) - mu * mu + EPS_);

    f32x4 hyv, cyv;
#pragma unroll
    for (int e = 0; e < 4; ++e) {
        int h = h0 + e;
        float cy = (cp[e] - mu) * rs * lncw[h] + lncb[h];
        float hy = sigf(ov[e]) * tanhf(cy);
        cyv[e] = cy; hyv[e] = hy;
    }
    *(f32x4*)(out + (size_t)b * H_ + h0)                        = hyv;
    *(f32x4*)(out + OUT_TH + (size_t)b * (H_ + AH_) + h0)       = hyv;
    *(f32x4*)(out + OUT_TC + (size_t)b * (H_ + AH_) + h0)       = cyv;
}

// ---------------------------------------------------------------------------
extern "C" void kernel_launch(void* const* d_in, const int* in_sizes, int n_in,
                              void* d_out, int out_size, void* d_ws, size_t ws_size,
                              hipStream_t stream) {
    const float* x          = (const float*)d_in[0];
    const float* total_h    = (const float*)d_in[1];
    const float* total_c    = (const float*)d_in[2];
    const float* w_ih       = (const float*)d_in[3];
    const float* w_hh       = (const float*)d_in[4];
    const float* b_ih       = (const float*)d_in[5];
    const float* b_hh       = (const float*)d_in[6];
    const float* ln_i_w     = (const float*)d_in[7];
    const float* ln_i_b     = (const float*)d_in[8];
    const float* ln_h_w     = (const float*)d_in[9];
    const float* ln_h_b     = (const float*)d_in[10];
    const float* ln_c_w     = (const float*)d_in[11];
    const float* ln_c_b     = (const float*)d_in[12];
    const float* norm_zw_w  = (const float*)d_in[13];
    const float* norm_zw_b  = (const float*)d_in[14];
    const float* norm_alpha_w = (const float*)d_in[15];
    const float* bias_zb_w  = (const float*)d_in[16];
    const float* bias_beta_w = (const float*)d_in[17];
    const float* a_w_ih     = (const float*)d_in[18];
    const float* a_w_hh     = (const float*)d_in[19];
    const float* a_ln_i_w   = (const float*)d_in[20];
    const float* a_ln_i_b   = (const float*)d_in[21];
    const float* a_ln_h_w   = (const float*)d_in[22];
    const float* a_ln_h_b   = (const float*)d_in[23];
    const float* a_ln_c_w   = (const float*)d_in[24];
    const float* a_ln_c_b   = (const float*)d_in[25];
    float* out = (float*)d_out;

    // ws layout (bytes, all 256-aligned); total ~254 MB
    char* ws = (char*)d_ws;
    unsigned short* XA  = (unsigned short*)(ws + 0);          // 4096x3072 bf16 [xhi|xhi|xlo]
    unsigned short* HXA = (unsigned short*)(ws + 25165824);   // 4096x3072
    unsigned short* WIH = (unsigned short*)(ws + 50331648);   // 4096x3072 [hi|lo|hi]
    unsigned short* WHH = (unsigned short*)(ws + 75497472);   // 4096x3072
    unsigned short* WAI = (unsigned short*)(ws + 100663296);  // 512x6144
    unsigned short* AHS = (unsigned short*)(ws + 106954752);  // 4096x384
    unsigned short* WAH = (unsigned short*)(ws + 110100480);  // 512x384
    float* IG    = (float*)(ws + 110493696);                  // 4096x512
    float* HG    = (float*)(ws + 118882304);                  // 4096x512
    float* XHp   = (float*)(ws + 127270912);                  // 4096x4096
    float* HHp   = (float*)(ws + 194379776);                  // 4096x4096
    float* ZW    = (float*)(ws + 261488640);                  // 4096x128
    float* ZB    = (float*)(ws + 263585792);                  // 4096x128
    float* STATS = (float*)(ws + 265682944);                  // 4096x4

    auto grid1 = [](long n) { return dim3((unsigned)((n + 255) / 256)); };

    // ---- splits (A pattern: hi@0,hi@K,lo@2K ; B pattern: hi@0,lo@K,hi@2K) --
    split3_kernel<<<grid1(4096L*1024), 256, 0, stream>>>(x,       1024, 0,    4096L*1024, 1024, XA,  3072, 0, 1024, 2048);
    split3_kernel<<<grid1(4096L*1024), 256, 0, stream>>>(total_h, 1152, 0,    4096L*1024, 1024, HXA, 3072, 0, 1024, 2048);
    split3_kernel<<<grid1(4096L*128),  256, 0, stream>>>(total_h, 1152, 1024, 4096L*128,  128,  AHS, 384,  0, 128,  256);
    split3_kernel<<<grid1(4096L*1024), 256, 0, stream>>>(w_ih,    1024, 0,    4096L*1024, 1024, WIH, 3072, 0, 2048, 1024);
    split3_kernel<<<grid1(4096L*1024), 256, 0, stream>>>(w_hh,    1024, 0,    4096L*1024, 1024, WHH, 3072, 0, 2048, 1024);
    split3_kernel<<<grid1(512L*1024),  256, 0, stream>>>(a_w_ih,  2048, 0,    512L*1024,  1024, WAI,        6144, 0, 2048, 1024);
    split3_kernel<<<grid1(512L*1024),  256, 0, stream>>>(a_w_ih,  2048, 1024, 512L*1024,  1024, WAI + 3072, 6144, 0, 2048, 1024);
    split3_kernel<<<grid1(512L*128),   256, 0, stream>>>(a_w_hh,  128,  0,    512L*128,   128,  WAH, 384,  0, 256,  128);

    // ---- GEMMs (3-term split is folded into K) ----
    const int BIG = 1 << 30;
    // ig = ai @ a_w_ih.T  (A = [XA | HXA] along K)
    gemm_bt_bf16<<<dim3(512/128, 4096/128), 256, 0, stream>>>(XA, HXA, 3072, 3072, WAI, 6144, IG, 512, 6144);
    // hg = ah @ a_w_hh.T
    gemm_bt_bf16<<<dim3(512/128, 4096/128), 256, 0, stream>>>(AHS, AHS, BIG, 384, WAH, 384, HG, 512, 384);
    // xh = x @ w_ih.T ; hh = hx @ w_hh.T
    gemm_bt_bf16<<<dim3(4096/128, 4096/128), 256, 0, stream>>>(XA,  XA,  BIG, 3072, WIH, 3072, XHp, 4096, 3072);
    gemm_bt_bf16<<<dim3(4096/128, 4096/128), 256, 0, stream>>>(HXA, HXA, BIG, 3072, WHH, 3072, HHp, 4096, 3072);

    // ---- adaptive path: acy/ada (writes out tails) + zw/zb ----
    adaptive_gates_kernel<<<4096, 64, 0, stream>>>(IG, HG, total_c,
        a_ln_i_w, a_ln_i_b, a_ln_h_w, a_ln_h_b, a_ln_c_w, a_ln_c_b,
        norm_zw_w, norm_zw_b, bias_zb_w, ZW, ZB, out);

    // ---- alpha/beta scale (in place on XHp/HHp) + LN4096 stats ----
    scale_stats_kernel<<<512, 512, 0, stream>>>(XHp, HHp, ZW, ZB,
        norm_alpha_w, bias_beta_w, b_ih, b_hh, STATS);

    // ---- final gates + outputs ----
    final_gates_kernel<<<4096, 256, 0, stream>>>(XHp, HHp, STATS,
        ln_i_w, ln_i_b, ln_h_w, ln_h_b, ln_c_w, ln_c_b, total_c, out);
}

// Round 3
// 668.643 us; speedup vs baseline: 1.2317x; 1.2317x over previous
//
#include <hip/hip_runtime.h>
#include <cstdint>
#include <cstddef>

// ---------------------------------------------------------------------------
// AdaptiveLSTMCell (B=4096, I=1024, H=1024, AH=128, AI=16), fp32 in/out.
//   * big GEMMs via bf16 MFMA with 3-term hi/lo split:
//       C = Ahi*Whi + Ahi*Wlo + Alo*Whi  (K -> 3K virtual concat)
//     panels stored compact [hi|lo] (2K wide); GEMM remaps K-tile pointer:
//       A off = kt<KA ? kt : kt-KA   (hi, hi, lo)
//       W off = kt<2KA ? kt : kt-2KA (hi, lo, hi)
//     -> ws total ~237 MB (R2's 262 MB overflowed d_ws and crashed)
//   * m97-style 128x128 tile GEMM, BK=32, global_load_lds(16B), XCD swizzle
//   * split kernels: 8 elem/thread, shift indexing (no i64 div)
//   * adaptive path fused per-row; zw/zb via pre-transposed weights
//   * alpha/beta never materialized; scale+stats in place, z via ds_read_b128
// ---------------------------------------------------------------------------

#define B_   4096
#define I_   1024
#define H_   1024
#define AH_  128
#define G4_  4096   // 4*H
#define EPS_ 1e-5f

// out layout: hy (B*H) | new_total_h (B*1152) | new_total_c (B*1152)
#define OUT_TH ((size_t)B_ * H_)
#define OUT_TC (OUT_TH + (size_t)B_ * (H_ + AH_))

typedef short s16x8 __attribute__((ext_vector_type(8)));
typedef float f32x4 __attribute__((ext_vector_type(4)));

// ---------------- helpers ----------------
__device__ __forceinline__ unsigned short f2bf_rn(float f) {
    unsigned int u = __builtin_bit_cast(unsigned int, f);
    unsigned int r = u + 0x7FFFu + ((u >> 16) & 1u);   // round-to-nearest-even
    return (unsigned short)(r >> 16);
}
__device__ __forceinline__ float bf2f(unsigned short h) {
    unsigned int u = ((unsigned int)h) << 16;
    return __builtin_bit_cast(float, u);
}
__device__ __forceinline__ float sigf(float x) { return 1.0f / (1.0f + expf(-x)); }

__device__ __forceinline__ void gld16(const void* g, void* l) {
    __builtin_amdgcn_global_load_lds(
        (const __attribute__((address_space(1))) unsigned int*)g,
        (__attribute__((address_space(3))) unsigned int*)l,
        16, 0, 0);
}

// ---------------- split: fp32 -> bf16 [hi|lo] panel, 8 elems/thread --------
__global__ void split8_kernel(const float* __restrict__ src, int srcStride, int srcOff,
                              long nThreads, int kshift,
                              unsigned short* __restrict__ dst, int dstStride,
                              int offHi, int offLo) {
    long t = (long)blockIdx.x * blockDim.x + threadIdx.x;
    if (t >= nThreads) return;
    int r  = (int)(t >> kshift);
    int kk = ((int)t & ((1 << kshift) - 1)) * 8;
    const float* sp = src + (size_t)r * srcStride + srcOff + kk;
    f32x4 v0 = *(const f32x4*)sp;
    f32x4 v1 = *(const f32x4*)(sp + 4);
    float v[8] = {v0[0], v0[1], v0[2], v0[3], v1[0], v1[1], v1[2], v1[3]};
    s16x8 hi, lo;
#pragma unroll
    for (int j = 0; j < 8; ++j) {
        unsigned short hu = f2bf_rn(v[j]);
        unsigned short lu = f2bf_rn(v[j] - bf2f(hu));
        hi[j] = (short)hu; lo[j] = (short)lu;
    }
    size_t base = (size_t)r * dstStride + kk;
    *(s16x8*)(dst + base + offHi) = hi;
    *(s16x8*)(dst + base + offLo) = lo;
}

// ---------------- transpose 128x128 zw_w / zb_w (a-major for coalescing) ---
__global__ void transpose128_kernel(const float* __restrict__ zw_w, const float* __restrict__ zb_w,
                                    float* __restrict__ ZWT, float* __restrict__ ZBT) {
    int t = blockIdx.x * 256 + threadIdx.x;   // 16384
    int idx = t >> 7, a = t & 127;
    ZWT[a * 128 + idx] = zw_w[idx * 128 + a];
    ZBT[a * 128 + idx] = zb_w[idx * 128 + a];
}

// ---------------- GEMM: C(MxN) = A(MxK3) * W(NxK3)^T, bf16 in, fp32 out ----
// 3-term split: virtual K = 3*KA. A panel [hi|lo] (2*KA wide): off = kt<KA?kt:kt-KA.
// W panel [hi|lo] (2*KA wide): off = kt<2KA?kt:kt-2KA.
// blockIdx.z selects A0/A1 + W column-chunk + C slab (for the K-split IG GEMM)
__launch_bounds__(256, 2)
__global__ void gemm_bt_bf16(const unsigned short* __restrict__ A0,
                             const unsigned short* __restrict__ A1,
                             int lda,
                             const unsigned short* __restrict__ W, int ldw, int wzOff,
                             float* __restrict__ C, int ldc, long czOff,
                             int K, int kA1, int kW1) {
    __shared__ __align__(16) unsigned short As[128 * 32];
    __shared__ __align__(16) unsigned short Bs[128 * 32];
    const unsigned short* A  = blockIdx.z ? A1 : A0;
    const unsigned short* Wp = W + (size_t)blockIdx.z * wzOff;
    float* Cp = C + (size_t)blockIdx.z * czOff;

    // XCD-aware swizzle over x*y (all grids here have nwg % 8 == 0)
    const int gx = gridDim.x;
    int lin = blockIdx.y * gx + blockIdx.x;
    const int cpx = (gx * gridDim.y) >> 3;
    lin = (lin & 7) * cpx + (lin >> 3);
    const int bx = lin % gx, by = lin / gx;

    const int tid  = threadIdx.x;
    const int lane = tid & 63;
    const int w    = tid >> 6;           // wave 0..3
    const int wr   = w >> 1, wc = w & 1; // wave -> 64x64 quadrant
    const int l15  = lane & 15;
    const int lk   = (lane >> 4) * 8;

    f32x4 acc[4][4] = {};

    for (int kt = 0; kt < K; kt += 32) {
        const unsigned short* Ab = A  + (kt < kA1 ? kt : kt - kA1);
        const unsigned short* Wb = Wp + (kt < kW1 ? kt : kt - kW1);
#pragma unroll
        for (int it = 0; it < 2; ++it) {
            int q = it * 256 + tid;
            int row = q >> 2, c8 = (q & 3) * 8;
            gld16(Ab + (size_t)(by * 128 + row) * lda + c8,
                  (char*)As + (size_t)(it * 256 + w * 64) * 16);
        }
#pragma unroll
        for (int it = 0; it < 2; ++it) {
            int q = it * 256 + tid;
            int row = q >> 2, c8 = (q & 3) * 8;
            gld16(Wb + (size_t)(bx * 128 + row) * ldw + c8,
                  (char*)Bs + (size_t)(it * 256 + w * 64) * 16);
        }
        __syncthreads();

        s16x8 afr[4], bfr[4];
#pragma unroll
        for (int m = 0; m < 4; ++m)
            afr[m] = *(const s16x8*)&As[(wr * 64 + m * 16 + l15) * 32 + lk];
#pragma unroll
        for (int n = 0; n < 4; ++n)
            bfr[n] = *(const s16x8*)&Bs[(wc * 64 + n * 16 + l15) * 32 + lk];
#pragma unroll
        for (int m = 0; m < 4; ++m)
#pragma unroll
            for (int n = 0; n < 4; ++n)
                acc[m][n] = __builtin_amdgcn_mfma_f32_16x16x32_bf16(
                    afr[m], bfr[n], acc[m][n], 0, 0, 0);
        __syncthreads();
    }

    const int r0 = by * 128 + wr * 64;
    const int c0 = bx * 128 + wc * 64;
    const int rl = (lane >> 4) * 4;
#pragma unroll
    for (int m = 0; m < 4; ++m)
#pragma unroll
        for (int n = 0; n < 4; ++n)
#pragma unroll
            for (int j = 0; j < 4; ++j)
                Cp[(size_t)(r0 + m * 16 + rl + j) * ldc + c0 + n * 16 + l15] = acc[m][n][j];
}

// ---------------- adaptive path: LN(ig)+LN(hg) -> gates -> acy/ada -> zw/zb
// one wave per batch row; IG comes as two K-partials (IGa + IGb)
__launch_bounds__(64)
__global__ void adaptive_gates_kernel(const float* __restrict__ IGa, const float* __restrict__ IGb,
                                      const float* __restrict__ HG,
                                      const float* __restrict__ total_c,
                                      const float* __restrict__ alniw, const float* __restrict__ alnib,
                                      const float* __restrict__ alnhw, const float* __restrict__ alnhb,
                                      const float* __restrict__ alncw, const float* __restrict__ alncb,
                                      const float* __restrict__ ZWT, const float* __restrict__ zw_b,
                                      const float* __restrict__ ZBT,
                                      float* __restrict__ ZW, float* __restrict__ ZB,
                                      float* __restrict__ out) {
    const int b    = blockIdx.x;
    const int lane = threadIdx.x;
    __shared__ float ada_lds[AH_];

    float ig[8], hg[8];
    const float* ipa = IGa + (size_t)b * 512 + lane * 8;
    const float* ipb = IGb + (size_t)b * 512 + lane * 8;
    const float* hgp = HG  + (size_t)b * 512 + lane * 8;
    float sI = 0, qI = 0, sH = 0, qH = 0;
#pragma unroll
    for (int j = 0; j < 8; ++j) {
        ig[j] = ipa[j] + ipb[j]; sI += ig[j]; qI += ig[j] * ig[j];
        hg[j] = hgp[j];          sH += hg[j]; qH += hg[j] * hg[j];
    }
#pragma unroll
    for (int m = 1; m < 64; m <<= 1) {
        sI += __shfl_xor(sI, m); qI += __shfl_xor(qI, m);
        sH += __shfl_xor(sH, m); qH += __shfl_xor(qH, m);
    }
    const float muI = sI * (1.0f / 512.0f);
    const float rI  = rsqrtf(qI * (1.0f / 512.0f) - muI * muI + EPS_);
    const float muH = sH * (1.0f / 512.0f);
    const float rH  = rsqrtf(qH * (1.0f / 512.0f) - muH * muH + EPS_);

    float g[8];
#pragma unroll
    for (int j = 0; j < 8; ++j) {
        int c = lane * 8 + j;
        g[j] = (ig[j] - muI) * rI * alniw[c] + alnib[c]
             + (hg[j] - muH) * rH * alnhw[c] + alnhb[c];
    }

    // adaptive gate split order: gi, gf, gj, go (chunks 0..3 of 512)
    const int l15 = lane & 15;
    float cp[8], gov[8];
    float s = 0, q = 0;
#pragma unroll
    for (int j = 0; j < 8; ++j) {
        float giv = __shfl(g[j], l15);
        float gfv = __shfl(g[j], 16 + l15);
        float gjv = __shfl(g[j], 32 + l15);
        gov[j]    = __shfl(g[j], 48 + l15);
        int a = l15 * 8 + j;
        float ac = total_c[(size_t)b * (H_ + AH_) + H_ + a];
        cp[j] = sigf(gfv) * ac + sigf(giv) * tanhf(gjv);
        s += cp[j]; q += cp[j] * cp[j];
    }
#pragma unroll
    for (int m = 1; m < 16; m <<= 1) { s += __shfl_xor(s, m); q += __shfl_xor(q, m); }
    const float mu = s * (1.0f / 128.0f);
    const float rs = rsqrtf(q * (1.0f / 128.0f) - mu * mu + EPS_);

    float adav[8], acyv[8];
#pragma unroll
    for (int j = 0; j < 8; ++j) {
        int a = l15 * 8 + j;
        acyv[j] = (cp[j] - mu) * rs * alncw[a] + alncb[a];
        adav[j] = sigf(gov[j]) * tanhf(acyv[j]);
    }
    if (lane < 16) {
#pragma unroll
        for (int j = 0; j < 8; ++j) {
            int a = lane * 8 + j;
            ada_lds[a] = adav[j];
            out[OUT_TH + (size_t)b * (H_ + AH_) + H_ + a] = adav[j];  // ada
            out[OUT_TC + (size_t)b * (H_ + AH_) + H_ + a] = acyv[j]; // acy
        }
    }
    __syncthreads();

    // zw/zb: each lane produces outputs (2*lane, 2*lane+1); coalesced float2
    float az0 = 0, az1 = 0, ab0 = 0, ab1 = 0;
#pragma unroll 4
    for (int a = 0; a < 128; ++a) {
        float ad = ada_lds[a];                 // wave-uniform broadcast
        float2 wz = *(const float2*)&ZWT[a * 128 + lane * 2];
        float2 wb = *(const float2*)&ZBT[a * 128 + lane * 2];
        az0 += ad * wz.x; az1 += ad * wz.y;
        ab0 += ad * wb.x; ab1 += ad * wb.y;
    }
    const int i0 = lane * 2, i1 = lane * 2 + 1;
    ZW[(size_t)b * 128 + i0] = az0 + zw_b[i0];
    ZW[(size_t)b * 128 + i1] = az1 + zw_b[i1];
    ZB[(size_t)b * 128 + i0] = ab0;
    ZB[(size_t)b * 128 + i1] = ab1;
}

// ---------------- scale xh/hh by alpha,+bias+beta (in place) + row stats ---
__launch_bounds__(512)
__global__ void scale_stats_kernel(float* __restrict__ XH, float* __restrict__ HH,
                                   const float* __restrict__ ZW, const float* __restrict__ ZB,
                                   const float* __restrict__ aw, const float* __restrict__ bw,
                                   const float* __restrict__ b_ih, const float* __restrict__ b_hh,
                                   float* __restrict__ STATS) {
    const int tid  = threadIdx.x;
    const int lane = tid & 63;
    const int w    = tid >> 6;     // 8 waves
    const int b0   = blockIdx.x * 8;

    __shared__ __align__(16) float zwl[8 * 128], zbl[8 * 128];
    __shared__ float part[8][8][4];
    __shared__ float tot[8][4];

    for (int t = tid; t < 1024; t += 512) {
        int r = t >> 7, si = t & 127;
        zwl[t] = ZW[(size_t)(b0 + r) * 128 + si];
        zbl[t] = ZB[(size_t)(b0 + r) * 128 + si];
    }
    __syncthreads();

    float sI[8] = {}, qI[8] = {}, sH[8] = {}, qH[8] = {};

    for (int strip = w; strip < 128; strip += 8) {   // 64 in_g strips, 64 hid_g
        const bool isIn = strip < 64;
        const int  c    = (isIn ? strip : strip - 64) * 64 + lane;   // 0..4095
        const int  se   = (c >> 10) + (isIn ? 0 : 4);                // s index 0..7
        float*       X    = isIn ? XH : HH;
        const float* bias = isIn ? b_ih : b_hh;
        const int    h    = c & 1023;

        const f32x4* awp = (const f32x4*)(aw + ((size_t)se * 1024 + h) * 16);
        const f32x4* bwp = (const f32x4*)(bw + ((size_t)se * 1024 + h) * 16);
        f32x4 a0 = awp[0], a1 = awp[1], a2 = awp[2], a3 = awp[3];
        f32x4 w0 = bwp[0], w1 = bwp[1], w2 = bwp[2], w3 = bwp[3];
        const float bc = bias[c];

#pragma unroll
        for (int r = 0; r < 8; ++r) {
            const f32x4* zp = (const f32x4*)&zwl[r * 128 + se * 16];
            const f32x4* yp = (const f32x4*)&zbl[r * 128 + se * 16];
            f32x4 z0 = zp[0], z1 = zp[1], z2 = zp[2], z3 = zp[3];
            f32x4 y0 = yp[0], y1 = yp[1], y2 = yp[2], y3 = yp[3];
            float alpha = a0[0]*z0[0] + a0[1]*z0[1] + a0[2]*z0[2] + a0[3]*z0[3]
                        + a1[0]*z1[0] + a1[1]*z1[1] + a1[2]*z1[2] + a1[3]*z1[3]
                        + a2[0]*z2[0] + a2[1]*z2[1] + a2[2]*z2[2] + a2[3]*z2[3]
                        + a3[0]*z3[0] + a3[1]*z3[1] + a3[2]*z3[2] + a3[3]*z3[3];
            float beta  = w0[0]*y0[0] + w0[1]*y0[1] + w0[2]*y0[2] + w0[3]*y0[3]
                        + w1[0]*y1[0] + w1[1]*y1[1] + w1[2]*y1[2] + w1[3]*y1[3]
                        + w2[0]*y2[0] + w2[1]*y2[1] + w2[2]*y2[2] + w2[3]*y2[3]
                        + w3[0]*y3[0] + w3[1]*y3[1] + w3[2]*y3[2] + w3[3]*y3[3];
            size_t off = (size_t)(b0 + r) * G4_ + c;
            float v = X[off] * alpha + bc + beta;
            X[off] = v;
            if (isIn) { sI[r] += v; qI[r] += v * v; }
            else      { sH[r] += v; qH[r] += v * v; }
        }
    }

#pragma unroll
    for (int r = 0; r < 8; ++r) {
#pragma unroll
        for (int m = 1; m < 64; m <<= 1) {
            sI[r] += __shfl_xor(sI[r], m); qI[r] += __shfl_xor(qI[r], m);
            sH[r] += __shfl_xor(sH[r], m); qH[r] += __shfl_xor(qH[r], m);
        }
        if (lane == 0) {
            part[w][r][0] = sI[r]; part[w][r][1] = qI[r];
            part[w][r][2] = sH[r]; part[w][r][3] = qH[r];
        }
    }
    __syncthreads();
    if (tid < 32) {
        int r = tid >> 2, cmp = tid & 3;
        float t = 0;
        for (int ww = 0; ww < 8; ++ww) t += part[ww][r][cmp];
        tot[r][cmp] = t;
    }
    __syncthreads();
    if (tid < 8) {
        int r = tid;
        float muI = tot[r][0] * (1.0f / 4096.0f);
        float vI  = tot[r][1] * (1.0f / 4096.0f) - muI * muI;
        float muH = tot[r][2] * (1.0f / 4096.0f);
        float vH  = tot[r][3] * (1.0f / 4096.0f) - muH * muH;
        f32x4 st = { muI, rsqrtf(vI + EPS_), muH, rsqrtf(vH + EPS_) };
        *(f32x4*)(STATS + (size_t)(b0 + r) * 4) = st;
    }
}

// ---------------- final: LN(in_g)+LN(hid_g) -> LSTM gates -> LN(c) -> out --
__launch_bounds__(256)
__global__ void final_gates_kernel(const float* __restrict__ XH, const float* __restrict__ HH,
                                   const float* __restrict__ STATS,
                                   const float* __restrict__ lniw, const float* __restrict__ lnib,
                                   const float* __restrict__ lnhw, const float* __restrict__ lnhb,
                                   const float* __restrict__ lncw, const float* __restrict__ lncb,
                                   const float* __restrict__ total_c,
                                   float* __restrict__ out) {
    const int b = blockIdx.x, tid = threadIdx.x;
    const int lane = tid & 63, w = tid >> 6;
    __shared__ float red[4][2];

    const f32x4 st = *(const f32x4*)(STATS + (size_t)b * 4); // muI,rI,muH,rH
    const int h0 = tid * 4;

    float gg[4][4];
#pragma unroll
    for (int s = 0; s < 4; ++s) {
        int c = s * 1024 + h0;
        f32x4 xi = *(const f32x4*)(XH + (size_t)b * G4_ + c);
        f32x4 hi = *(const f32x4*)(HH + (size_t)b * G4_ + c);
        f32x4 wi = *(const f32x4*)(lniw + c);
        f32x4 bi = *(const f32x4*)(lnib + c);
        f32x4 wh = *(const f32x4*)(lnhw + c);
        f32x4 bh = *(const f32x4*)(lnhb + c);
#pragma unroll
        for (int e = 0; e < 4; ++e)
            gg[s][e] = (xi[e] - st[0]) * st[1] * wi[e] + bi[e]
                     + (hi[e] - st[2]) * st[3] * wh[e] + bh[e];
    }

    // main LSTM split order: i, j, f, o (chunks 0..3)
    float cp[4], ov[4];
    float s_ = 0, q_ = 0;
#pragma unroll
    for (int e = 0; e < 4; ++e) {
        float iv = gg[0][e], jv = gg[1][e], fv = gg[2][e];
        ov[e] = gg[3][e];
        float cx = total_c[(size_t)b * (H_ + AH_) + h0 + e];
        cp[e] = sigf(fv) * cx + sigf(iv) * tanhf(jv);
        s_ += cp[e]; q_ += cp[e] * cp[e];
    }
#pragma unroll
    for (int m = 1; m < 64; m <<= 1) { s_ += __shfl_xor(s_, m); q_ += __shfl_xor(q_, m); }
    if (lane == 0) { red[w][0] = s_; red[w][1] = q_; }
    __syncthreads();
    float S = red[0][0] + red[1][0] + red[2][0] + red[3][0];
    float Q = red[0][1] + red[1][1] + red[2][1] + red[3][1];
    float mu = S * (1.0f / 1024.0f);
    float rs = rsqrtf(Q * (1.0f / 1024.0f) - mu * mu + EPS_);

    f32x4 hyv, cyv;
#pragma unroll
    for (int e = 0; e < 4; ++e) {
        int h = h0 + e;
        float cy = (cp[e] - mu) * rs * lncw[h] + lncb[h];
        float hy = sigf(ov[e]) * tanhf(cy);
        cyv[e] = cy; hyv[e] = hy;
    }
    *(f32x4*)(out + (size_t)b * H_ + h0)                  = hyv;
    *(f32x4*)(out + OUT_TH + (size_t)b * (H_ + AH_) + h0) = hyv;
    *(f32x4*)(out + OUT_TC + (size_t)b * (H_ + AH_) + h0) = cyv;
}

// ---------------------------------------------------------------------------
extern "C" void kernel_launch(void* const* d_in, const int* in_sizes, int n_in,
                              void* d_out, int out_size, void* d_ws, size_t ws_size,
                              hipStream_t stream) {
    const float* x          = (const float*)d_in[0];
    const float* total_h    = (const float*)d_in[1];
    const float* total_c    = (const float*)d_in[2];
    const float* w_ih       = (const float*)d_in[3];
    const float* w_hh       = (const float*)d_in[4];
    const float* b_ih       = (const float*)d_in[5];
    const float* b_hh       = (const float*)d_in[6];
    const float* ln_i_w     = (const float*)d_in[7];
    const float* ln_i_b     = (const float*)d_in[8];
    const float* ln_h_w     = (const float*)d_in[9];
    const float* ln_h_b     = (const float*)d_in[10];
    const float* ln_c_w     = (const float*)d_in[11];
    const float* ln_c_b     = (const float*)d_in[12];
    const float* norm_zw_w  = (const float*)d_in[13];
    const float* norm_zw_b  = (const float*)d_in[14];
    const float* norm_alpha_w = (const float*)d_in[15];
    const float* bias_zb_w  = (const float*)d_in[16];
    const float* bias_beta_w = (const float*)d_in[17];
    const float* a_w_ih     = (const float*)d_in[18];
    const float* a_w_hh     = (const float*)d_in[19];
    const float* a_ln_i_w   = (const float*)d_in[20];
    const float* a_ln_i_b   = (const float*)d_in[21];
    const float* a_ln_h_w   = (const float*)d_in[22];
    const float* a_ln_h_b   = (const float*)d_in[23];
    const float* a_ln_c_w   = (const float*)d_in[24];
    const float* a_ln_c_b   = (const float*)d_in[25];
    float* out = (float*)d_out;

    // ws layout (bytes); total ~237.4 MB (R1-proven bound is 265.7 MB)
    char* ws = (char*)d_ws;
    unsigned short* XA  = (unsigned short*)(ws + 0);          // 4096x2048 [hi|lo]
    unsigned short* HXA = (unsigned short*)(ws + 16777216);   // 4096x2048
    unsigned short* WIH = (unsigned short*)(ws + 33554432);   // 4096x2048
    unsigned short* WHH = (unsigned short*)(ws + 50331648);   // 4096x2048
    unsigned short* WAI = (unsigned short*)(ws + 67108864);   // 512x4096 (x[hi|lo] | h[hi|lo])
    unsigned short* AHS = (unsigned short*)(ws + 71303168);   // 4096x256
    unsigned short* WAH = (unsigned short*)(ws + 73400320);   // 512x256
    float* IG    = (float*)(ws + 73662464);                   // 2 x 4096x512 (K-partials)
    float* HG    = (float*)(ws + 90439680);                   // 4096x512
    float* XHp   = (float*)(ws + 98828288);                   // 4096x4096
    float* HHp   = (float*)(ws + 165937152);                  // 4096x4096
    float* ZW    = (float*)(ws + 233046016);                  // 4096x128
    float* ZB    = (float*)(ws + 235143168);                  // 4096x128
    float* STATS = (float*)(ws + 237240320);                  // 4096x4
    float* ZWT   = (float*)(ws + 237305856);                  // 128x128 transposed
    float* ZBT   = (float*)(ws + 237371392);                  // 128x128 transposed

    auto grid8 = [](long n) { return dim3((unsigned)((n / 8 + 255) / 256)); };

    // ---- splits: [hi|lo] compact panels --------------------------------
    split8_kernel<<<grid8(4096L*1024), 256, 0, stream>>>(x,       1024, 0,    4096L*128, 7, XA,  2048, 0, 1024);
    split8_kernel<<<grid8(4096L*1024), 256, 0, stream>>>(total_h, 1152, 0,    4096L*128, 7, HXA, 2048, 0, 1024);
    split8_kernel<<<grid8(4096L*128),  256, 0, stream>>>(total_h, 1152, 1024, 4096L*16,  4, AHS, 256,  0, 128);
    split8_kernel<<<grid8(4096L*1024), 256, 0, stream>>>(w_ih,    1024, 0,    4096L*128, 7, WIH, 2048, 0, 1024);
    split8_kernel<<<grid8(4096L*1024), 256, 0, stream>>>(w_hh,    1024, 0,    4096L*128, 7, WHH, 2048, 0, 1024);
    split8_kernel<<<grid8(512L*1024),  256, 0, stream>>>(a_w_ih,  2048, 0,    512L*128,  7, WAI, 4096, 0,    1024);
    split8_kernel<<<grid8(512L*1024),  256, 0, stream>>>(a_w_ih,  2048, 1024, 512L*128,  7, WAI, 4096, 2048, 3072);
    split8_kernel<<<grid8(512L*128),   256, 0, stream>>>(a_w_hh,  128,  0,    512L*16,   4, WAH, 256,  0, 128);
    transpose128_kernel<<<64, 256, 0, stream>>>(norm_zw_w, bias_zb_w, ZWT, ZBT);

    // ---- GEMMs (3-term split: K=3*KA virtual; kA1=KA, kW1=2*KA) --------
    // ig partials: z=0 -> x-part, z=1 -> hx-part (summed in adaptive_gates)
    gemm_bt_bf16<<<dim3(4, 32, 2), 256, 0, stream>>>(XA, HXA, 2048, WAI, 4096, 2048, IG, 512, 4096L*512, 3072, 1024, 2048);
    // hg = ah @ a_w_hh.T
    gemm_bt_bf16<<<dim3(4, 32, 1), 256, 0, stream>>>(AHS, AHS, 256, WAH, 256, 0, HG, 512, 0, 384, 128, 256);
    // xh = x @ w_ih.T ; hh = hx @ w_hh.T
    gemm_bt_bf16<<<dim3(32, 32, 1), 256, 0, stream>>>(XA,  XA,  2048, WIH, 2048, 0, XHp, 4096, 0, 3072, 1024, 2048);
    gemm_bt_bf16<<<dim3(32, 32, 1), 256, 0, stream>>>(HXA, HXA, 2048, WHH, 2048, 0, HHp, 4096, 0, 3072, 1024, 2048);

    // ---- adaptive path: acy/ada (writes out tails) + zw/zb -------------
    adaptive_gates_kernel<<<4096, 64, 0, stream>>>(IG, IG + 4096L*512, HG, total_c,
        a_ln_i_w, a_ln_i_b, a_ln_h_w, a_ln_h_b, a_ln_c_w, a_ln_c_b,
        ZWT, norm_zw_b, ZBT, ZW, ZB, out);

    // ---- alpha/beta scale (in place on XHp/HHp) + LN4096 stats ---------
    scale_stats_kernel<<<512, 512, 0, stream>>>(XHp, HHp, ZW, ZB,
        norm_alpha_w, bias_beta_w, b_ih, b_hh, STATS);

    // ---- final gates + outputs -----------------------------------------
    final_gates_kernel<<<4096, 256, 0, stream>>>(XHp, HHp, STATS,
        ln_i_w, ln_i_b, ln_h_w, ln_h_b, ln_c_w, ln_c_b, total_c, out);
}